// Round 2
// baseline (90.129 us; speedup 1.0000x reference)
//
#include <hip/hip_runtime.h>
#include <hip/hip_fp16.h>

#define BLOCK 256
#define MAXB 64

typedef int iv4 __attribute__((ext_vector_type(4)));

// ---------------------------------------------------------------------------
// Site accessors: packed (float4 {x,y,z, half2(sigma,eps)}) and raw fallback.
// ---------------------------------------------------------------------------
struct PackedSites {
    const float4* __restrict__ site;
    __device__ __forceinline__ float energy(int s, int d) const {
        float4 a = site[s];
        float4 b = site[d];
        float dx = a.x - b.x, dy = a.y - b.y, dz = a.z - b.z;
        float r2 = dx * dx + dy * dy + dz * dz;
        __half2 ha = __builtin_bit_cast(__half2, a.w);
        __half2 hb = __builtin_bit_cast(__half2, b.w);
        float sig = 0.5f * (__low2float(ha) + __low2float(hb));
        float eps = sqrtf(__high2float(ha) * __high2float(hb));
        float s2 = sig * sig / r2;
        float x6 = s2 * s2 * s2;
        return 4.0f * eps * (x6 * x6 - x6);
    }
};

struct RawSites {
    const float* __restrict__ pos;   // [N,3]
    const float* __restrict__ par;   // [N,2] (sigma, eps)
    __device__ __forceinline__ float energy(int s, int d) const {
        float ax = pos[3 * s], ay = pos[3 * s + 1], az = pos[3 * s + 2];
        float bx = pos[3 * d], by = pos[3 * d + 1], bz = pos[3 * d + 2];
        float dx = ax - bx, dy = ay - by, dz = az - bz;
        float r2 = dx * dx + dy * dy + dz * dz;
        float sa = par[2 * s], ea = par[2 * s + 1];
        float sb = par[2 * d], eb = par[2 * d + 1];
        float sig = 0.5f * (sa + sb);
        float eps = sqrtf(ea * eb);
        float s2 = sig * sig / r2;
        float x6 = s2 * s2 * s2;
        return 4.0f * eps * (x6 * x6 - x6);
    }
};

// ---------------------------------------------------------------------------
// Pack sites: pos fp32 + (sigma,eps) fp16x2 into one 16B record per site.
// ---------------------------------------------------------------------------
__global__ __launch_bounds__(BLOCK) void pack_sites_kernel(
    const float* __restrict__ pos, const float* __restrict__ par,
    float4* __restrict__ site, int N)
{
    int i = blockIdx.x * BLOCK + threadIdx.x;
    if (i >= N) return;
    __half2 h = __floats2half2_rn(par[2 * i], par[2 * i + 1]);  // low=sigma, high=eps
    float4 v;
    v.x = pos[3 * i];
    v.y = pos[3 * i + 1];
    v.z = pos[3 * i + 2];
    v.w = __builtin_bit_cast(float, h);
    site[i] = v;
}

// ---------------------------------------------------------------------------
// Main kernel: each block owns a contiguous quad range. batch is SORTED, so
// most blocks see a single batch id (fast path: skip batch stream entirely).
// ---------------------------------------------------------------------------
template <class S>
__global__ __launch_bounds__(BLOCK) void lj_main_kernel(
    S sites,
    const int* __restrict__ src,
    const int* __restrict__ dst,
    const int* __restrict__ batch,
    float* __restrict__ out,
    int nquads, int qpb, int B)
{
    __shared__ float bins[MAXB];
    for (int i = threadIdx.x; i < MAXB; i += BLOCK) bins[i] = 0.0f;
    __syncthreads();

    int q0 = blockIdx.x * qpb;
    int q1 = min(q0 + qpb, nquads);
    if (q0 < q1) {
        const int b_lo = batch[4 * q0];
        const int b_hi = batch[4 * q1 - 1];
        const iv4* s4p = (const iv4*)src;
        const iv4* d4p = (const iv4*)dst;

        if (b_lo == b_hi) {
            // -------- fast path: uniform batch id, no batch stream --------
            float acc = 0.0f;
            for (int q = q0 + (int)threadIdx.x; q < q1; q += BLOCK) {
                iv4 s4 = __builtin_nontemporal_load(&s4p[q]);
                iv4 d4 = __builtin_nontemporal_load(&d4p[q]);
                acc += sites.energy(s4.x, d4.x);
                acc += sites.energy(s4.y, d4.y);
                acc += sites.energy(s4.z, d4.z);
                acc += sites.energy(s4.w, d4.w);
            }
            #pragma unroll
            for (int off = 32; off > 0; off >>= 1) acc += __shfl_xor(acc, off);
            if ((threadIdx.x & 63) == 0) atomicAdd(&bins[b_lo], acc);
        } else {
            // -------- slow path: segment boundary inside this chunk --------
            const iv4* b4p = (const iv4*)batch;
            float acc = 0.0f;
            int bcur = -1;
            for (int q = q0 + (int)threadIdx.x; q < q1; q += BLOCK) {
                iv4 s4 = __builtin_nontemporal_load(&s4p[q]);
                iv4 d4 = __builtin_nontemporal_load(&d4p[q]);
                iv4 b4 = __builtin_nontemporal_load(&b4p[q]);
                int ss[4] = {s4.x, s4.y, s4.z, s4.w};
                int dd[4] = {d4.x, d4.y, d4.z, d4.w};
                int bb[4] = {b4.x, b4.y, b4.z, b4.w};
                #pragma unroll
                for (int j = 0; j < 4; ++j) {
                    int b = bb[j];
                    if (b != bcur) {
                        if (bcur >= 0) atomicAdd(&bins[bcur], acc);
                        bcur = b;
                        acc = 0.0f;
                    }
                    acc += sites.energy(ss[j], dd[j]);
                }
            }
            // final flush: wave-reduce when the whole wave agrees on b
            int b0 = __shfl(bcur, 0);
            bool uni = __all(bcur == b0);
            if (uni) {
                if (b0 >= 0) {
                    #pragma unroll
                    for (int off = 32; off > 0; off >>= 1) acc += __shfl_xor(acc, off);
                    if ((threadIdx.x & 63) == 0) atomicAdd(&bins[b0], acc);
                }
            } else if (bcur >= 0) {
                atomicAdd(&bins[bcur], acc);
            }
        }
    }
    __syncthreads();
    for (int i = threadIdx.x; i < MAXB && i < B; i += BLOCK) {
        float v = bins[i];
        if (v != 0.0f) unsafeAtomicAdd(&out[i], v);
    }
}

// Scalar range kernel: tail edges and generic fallback (B > MAXB).
template <class S>
__global__ __launch_bounds__(BLOCK) void lj_range_kernel(
    S sites,
    const int* __restrict__ src,
    const int* __restrict__ dst,
    const int* __restrict__ batch,
    float* __restrict__ out,
    int e0, int E)
{
    int e = e0 + blockIdx.x * BLOCK + (int)threadIdx.x;
    if (e < E) {
        float c = sites.energy(src[e], dst[e]);
        unsafeAtomicAdd(&out[batch[e]], c);
    }
}

template <class S>
static void launch_all(S sites, const int* src, const int* dst, const int* batch,
                       float* out, int E, int B, hipStream_t stream)
{
    int nquads = E >> 2;
    int tail = E & 3;
    if (B <= MAXB && nquads > 0) {
        int qpb = (nquads + 2047) / 2048;
        int nb = (nquads + qpb - 1) / qpb;
        lj_main_kernel<S><<<nb, BLOCK, 0, stream>>>(sites, src, dst, batch, out,
                                                    nquads, qpb, B);
    } else if (nquads > 0) {
        int ne = 4 * nquads;
        lj_range_kernel<S><<<(ne + BLOCK - 1) / BLOCK, BLOCK, 0, stream>>>(
            sites, src, dst, batch, out, 0, ne);
    }
    if (tail) {
        lj_range_kernel<S><<<1, BLOCK, 0, stream>>>(sites, src, dst, batch, out,
                                                    4 * nquads, E);
    }
}

extern "C" void kernel_launch(void* const* d_in, const int* in_sizes, int n_in,
                              void* d_out, int out_size, void* d_ws, size_t ws_size,
                              hipStream_t stream) {
    const float* pos   = (const float*)d_in[0];   // [N,3] fp32
    const float* par   = (const float*)d_in[1];   // [N,2] fp32
    const int*   eidx  = (const int*)d_in[2];     // [2,E] int32
    const int*   batch = (const int*)d_in[3];     // [E] int32, sorted
    const int N = in_sizes[0] / 3;
    const int E = in_sizes[3];
    const int* src = eidx;
    const int* dst = eidx + E;
    float* out = (float*)d_out;
    const int B = out_size;

    (void)hipMemsetAsync(d_out, 0, (size_t)out_size * sizeof(float), stream);
    if (E <= 0 || B <= 0) return;

    if (ws_size >= (size_t)N * sizeof(float4)) {
        float4* site = (float4*)d_ws;
        pack_sites_kernel<<<(N + BLOCK - 1) / BLOCK, BLOCK, 0, stream>>>(pos, par, site, N);
        PackedSites S{site};
        launch_all(S, src, dst, batch, out, E, B, stream);
    } else {
        RawSites S{pos, par};
        launch_all(S, src, dst, batch, out, E, B, stream);
    }
}